// Round 11
// baseline (1220.771 us; speedup 1.0000x reference)
//
#include <hip/hip_runtime.h>
#include <hip/hip_bf16.h>
#include <stdint.h>

#define T_STEPS 256
#define B_SZ    256
#define NI      128
#define NR      512
#define NO      64
#define BT      16    // batch rows per group
#define HALF_R  256   // K-half (and finalize-half) per block

typedef __attribute__((ext_vector_type(8))) short short8;
typedef __attribute__((ext_vector_type(4))) short short4v;
typedef __attribute__((ext_vector_type(4))) float f32x4;

__device__ __forceinline__ unsigned short f2bf(float f) {
    union { float f; unsigned u; } v; v.f = f;
    unsigned u = v.u;
    return (unsigned short)((u + 0x7FFFu + ((u >> 16) & 1u)) >> 16);
}

__device__ __forceinline__ unsigned long long tagpack2(float a, float b, unsigned tag) {
    const unsigned ua = (__float_as_uint(a) & ~1u) | tag;
    const unsigned ub = (__float_as_uint(b) & ~1u) | tag;
    return (unsigned long long)ua | ((unsigned long long)ub << 32);
}

// ---------------------------------------------------------------------------
// proj GEMM: proj[t*B+b][n] = (bf16(inputs[t,b,:]) @ bf16(Wi)^T)[n] + bi[n]
//            + (t<4 ? noise[t,b,n] : 0).   M=65536, N=512, K=128.
// ---------------------------------------------------------------------------
__global__ __launch_bounds__(256) void proj_gemm(
    const float* __restrict__ inputs, const float* __restrict__ Wi,
    const float* __restrict__ bi, const float* __restrict__ noise,
    float* __restrict__ proj)
{
    const int mb = blockIdx.x;
    const int nb = blockIdx.y;
    const int m0 = mb * 64, n0 = nb * 128;
    const int tid = threadIdx.x, w = tid >> 6, l = tid & 63;
    const int l15 = l & 15, l4 = l >> 4;

    __shared__ __align__(16) unsigned char Al[64 * 256];    // 16 KB bf16 swizzled
    __shared__ __align__(16) unsigned char Wl[128 * 256];   // 32 KB bf16 swizzled

    #pragma unroll
    for (int j = 0; j < 8; ++j) {
        const int f = j * 256 + tid;
        const int row = f >> 5, c4 = f & 31;
        const float4 v = *(const float4*)(inputs + (size_t)(m0 + row) * NI + c4 * 4);
        short4v pk;
        pk[0] = (short)f2bf(v.x); pk[1] = (short)f2bf(v.y);
        pk[2] = (short)f2bf(v.z); pk[3] = (short)f2bf(v.w);
        *(short4v*)(&Al[row * 256 + (((unsigned)(c4 * 8)) ^ ((row & 7) << 4))]) = pk;
    }
    #pragma unroll
    for (int j = 0; j < 16; ++j) {
        const int f = j * 256 + tid;
        const int r = f >> 5, c4 = f & 31;
        const float4 v = *(const float4*)(Wi + (size_t)(n0 + r) * NI + c4 * 4);
        short4v pk;
        pk[0] = (short)f2bf(v.x); pk[1] = (short)f2bf(v.y);
        pk[2] = (short)f2bf(v.z); pk[3] = (short)f2bf(v.w);
        *(short4v*)(&Wl[r * 256 + (((unsigned)(c4 * 8)) ^ ((r & 7) << 4))]) = pk;
    }
    __syncthreads();

    f32x4 acc[8];
    #pragma unroll
    for (int nt = 0; nt < 8; ++nt) acc[nt] = (f32x4){0.f, 0.f, 0.f, 0.f};
    #pragma unroll
    for (int kt = 0; kt < 4; ++kt) {
        const short8 a = *(const short8*)(
            &Al[(w * 16 + l15) * 256 + (((unsigned)(kt * 64 + l4 * 16)) ^ ((l15 & 7) << 4))]);
        #pragma unroll
        for (int nt = 0; nt < 8; ++nt) {
            const short8 b = *(const short8*)(
                &Wl[(nt * 16 + l15) * 256 + (((unsigned)(kt * 64 + l4 * 16)) ^ ((l15 & 7) << 4))]);
            acc[nt] = __builtin_amdgcn_mfma_f32_16x16x32_bf16(a, b, acc[nt], 0, 0, 0);
        }
    }

    const int t = m0 >> 8;   // 64-row tiles never cross a t boundary
    #pragma unroll
    for (int nt = 0; nt < 8; ++nt) {
        const int n = n0 + nt * 16 + l15;
        const float bv = bi[n];
        #pragma unroll
        for (int q = 0; q < 4; ++q) {
            const int gr = m0 + w * 16 + l4 * 4 + q;
            float v = acc[nt][q] + bv;
            if (t < 4) v += noise[(size_t)gr * NR + n];
            proj[(size_t)gr * NR + n] = v;
        }
    }
}

// ---------------------------------------------------------------------------
// Persistent scan, K-SPLIT partial-sum exchange.
// 32 blocks x 512 thr; block = (grp = bid&15, half = bid>>4).
// Block holds Wrec[:, half*256 : half*256+256] (all 512 n, its K-half) in regs.
// Per step: all waves 32 MFMAs (wave w covers n in [w*64, w*64+64)).
//   export waves ((w>>2) != half): partials for partner-finalized cols ->
//     per-ct tagged f32 exports to IF (tag = f32 mantissa LSB; setprio(1)).
//   keep waves ((w>>2) == half): own partials; poll partner partials; h =
//     relu(own + partner + proj) in registers -> pack bf16 into LDS (next
//     step's A-fragments) + f32 h store. ONE barrier per step.
// h never crosses blocks; the IF transit overlaps the keep-MFMA phase.
// ---------------------------------------------------------------------------
__global__ __launch_bounds__(512, 2) void rnn_scan(
    const float* __restrict__ Wrec,
    float* __restrict__ dout,
    unsigned long long* __restrict__ Xbuf)
{
    const int bid  = blockIdx.x;
    const int grp  = bid & 15;
    const int half = bid >> 4;
    const int b0   = grp * BT;
    const int tid  = threadIdx.x;
    const int w    = tid >> 6;
    const int l    = tid & 63;
    const int l15  = l & 15;
    const int l4   = l >> 4;
    const bool keep = ((w >> 2) == half);
    const int kw   = w & 3;
    const int mrow = l4 * 4;
    const int nb   = w * 64;                // this wave's global col base

    __shared__ __align__(16) unsigned char Hl[2][BT * 512];   // 16 KB dbuf

    // Wrec[n in my wave's 64 cols][my K-half] -> register B-fragments
    short8 Bh[4][8];
    #pragma unroll
    for (int ct = 0; ct < 4; ++ct) {
        const int n = nb + ct * 16 + l15;
        #pragma unroll
        for (int kt = 0; kt < 8; ++kt) {
            const float* src = Wrec + (size_t)n * NR + half * HALF_R + kt * 32 + l4 * 8;
            short8 f;
            #pragma unroll
            for (int j = 0; j < 8; ++j) f[j] = (short)f2bf(src[j]);
            Bh[ct][kt] = f;
        }
    }

    // exchange: per grp: [parity][dir] x 2048 u64 (16 rows x 256 cols f32)
    unsigned long long* Xg = Xbuf + (size_t)grp * 8192;

    float* hbuf   = dout + (size_t)NO * B_SZ;                 // proj in / h out
    float* hidout = hbuf + (size_t)T_STEPS * B_SZ * NR;

    float pj[4][4];

    // ---- prologue: t=0, h0 = relu(proj0); keep waves produce their half.
    if (keep) {
        #pragma unroll
        for (int ct = 0; ct < 4; ++ct)
            #pragma unroll
            for (int q = 0; q < 4; ++q)
                pj[ct][q] = hbuf[(size_t)(b0 + mrow + q) * NR + nb + ct * 16 + l15];
        #pragma unroll
        for (int ct = 0; ct < 4; ++ct) {
            #pragma unroll
            for (int q = 0; q < 4; ++q) {
                const float v = fmaxf(pj[ct][q], 0.f);
                hbuf[(size_t)(b0 + mrow + q) * NR + nb + ct * 16 + l15] = v;
                const float vo = __shfl_xor(v, 1, 64);
                unsigned pk = (unsigned)f2bf(v) | ((unsigned)f2bf(vo) << 16);
                const unsigned pk_hi = __shfl_xor(pk, 2, 64);
                if ((l & 3) == 0) {
                    const int c = kw * 64 + ct * 16 + l15;    // local k, %4==0
                    const int m = mrow + q;
                    const unsigned off = m * 512 +
                        (((unsigned)(2 * c)) ^ ((unsigned)((m & 7) << 4)));
                    *(unsigned long long*)(&Hl[0][off]) =
                        (unsigned long long)pk | ((unsigned long long)pk_hi << 32);
                }
            }
        }
        // prefetch proj(t=1)
        #pragma unroll
        for (int ct = 0; ct < 4; ++ct)
            #pragma unroll
            for (int q = 0; q < 4; ++q)
                pj[ct][q] = hbuf[((size_t)B_SZ + b0 + mrow + q) * NR + nb + ct * 16 + l15];
    }
    asm volatile("s_waitcnt lgkmcnt(0)" ::: "memory");
    __builtin_amdgcn_sched_barrier(0);
    __builtin_amdgcn_s_barrier();
    __builtin_amdgcn_sched_barrier(0);

    for (int t = 1; t < T_STEPS; ++t) {
        const int p = t & 1;
        const unsigned tag = ((unsigned)(t + 1) >> 1) & 1u;
        const unsigned char* Hb = &Hl[p ^ 1][0];

        f32x4 acc[4];
        #pragma unroll
        for (int ct = 0; ct < 4; ++ct) acc[ct] = (f32x4){0.f, 0.f, 0.f, 0.f};

        unsigned long long* Xe =
            Xg + (size_t)(p * 2 + (half ^ 1)) * 2048 + kw * 512 + l;

        if (!keep) __builtin_amdgcn_s_setprio(1);
        #pragma unroll
        for (int ct = 0; ct < 4; ++ct) {
            #pragma unroll
            for (int kt = 0; kt < 8; ++kt) {
                const unsigned off = l15 * 512 +
                    (((unsigned)(kt * 64 + l4 * 16)) ^ ((unsigned)((l15 & 7) << 4)));
                const short8 a = *(const short8*)(Hb + off);
                acc[ct] = __builtin_amdgcn_mfma_f32_16x16x32_bf16(a, Bh[ct][kt], acc[ct], 0, 0, 0);
            }
            if (!keep) {
                // export this ct's partials as soon as they're final
                __hip_atomic_store(Xe + ct * 128,
                                   tagpack2(acc[ct][0], acc[ct][1], tag),
                                   __ATOMIC_RELAXED, __HIP_MEMORY_SCOPE_AGENT);
                __hip_atomic_store(Xe + ct * 128 + 64,
                                   tagpack2(acc[ct][2], acc[ct][3], tag),
                                   __ATOMIC_RELAXED, __HIP_MEMORY_SCOPE_AGENT);
            }
        }
        if (!keep) __builtin_amdgcn_s_setprio(0);

        if (keep) {
            const unsigned long long* Xc =
                Xg + (size_t)(p * 2 + half) * 2048 + kw * 512 + l;
            const unsigned long long tmask =
                tag ? 0x0000000100000001ULL : 0ULL;
            unsigned long long d0, d1, d2, d3, d4, d5, d6, d7;
            for (;;) {
                d0 = __hip_atomic_load(Xc +   0, __ATOMIC_RELAXED, __HIP_MEMORY_SCOPE_AGENT);
                d1 = __hip_atomic_load(Xc +  64, __ATOMIC_RELAXED, __HIP_MEMORY_SCOPE_AGENT);
                d2 = __hip_atomic_load(Xc + 128, __ATOMIC_RELAXED, __HIP_MEMORY_SCOPE_AGENT);
                d3 = __hip_atomic_load(Xc + 192, __ATOMIC_RELAXED, __HIP_MEMORY_SCOPE_AGENT);
                d4 = __hip_atomic_load(Xc + 256, __ATOMIC_RELAXED, __HIP_MEMORY_SCOPE_AGENT);
                d5 = __hip_atomic_load(Xc + 320, __ATOMIC_RELAXED, __HIP_MEMORY_SCOPE_AGENT);
                d6 = __hip_atomic_load(Xc + 384, __ATOMIC_RELAXED, __HIP_MEMORY_SCOPE_AGENT);
                d7 = __hip_atomic_load(Xc + 448, __ATOMIC_RELAXED, __HIP_MEMORY_SCOPE_AGENT);
                const unsigned long long bad =
                    (((d0 ^ tmask) | (d1 ^ tmask) | (d2 ^ tmask) | (d3 ^ tmask) |
                      (d4 ^ tmask) | (d5 ^ tmask) | (d6 ^ tmask) | (d7 ^ tmask))
                     & 0x0000000100000001ULL);
                if (bad == 0) break;
            }

            float vv[4][4];
            #pragma unroll
            for (int ct = 0; ct < 4; ++ct) {
                const unsigned long long da = (ct == 0) ? d0 : (ct == 1) ? d2 : (ct == 2) ? d4 : d6;
                const unsigned long long db = (ct == 0) ? d1 : (ct == 1) ? d3 : (ct == 2) ? d5 : d7;
                vv[ct][0] = fmaxf(acc[ct][0] + __uint_as_float((unsigned)da)         + pj[ct][0], 0.f);
                vv[ct][1] = fmaxf(acc[ct][1] + __uint_as_float((unsigned)(da >> 32)) + pj[ct][1], 0.f);
                vv[ct][2] = fmaxf(acc[ct][2] + __uint_as_float((unsigned)db)         + pj[ct][2], 0.f);
                vv[ct][3] = fmaxf(acc[ct][3] + __uint_as_float((unsigned)(db >> 32)) + pj[ct][3], 0.f);
            }

            // pack h[t] (bf16) into Hl[p] as next step's A-fragments
            #pragma unroll
            for (int ct = 0; ct < 4; ++ct) {
                #pragma unroll
                for (int q = 0; q < 4; ++q) {
                    const float v = vv[ct][q];
                    const float vo = __shfl_xor(v, 1, 64);
                    unsigned pk = (unsigned)f2bf(v) | ((unsigned)f2bf(vo) << 16);
                    const unsigned pk_hi = __shfl_xor(pk, 2, 64);
                    if ((l & 3) == 0) {
                        const int c = kw * 64 + ct * 16 + l15;
                        const int m = mrow + q;
                        const unsigned off = m * 512 +
                            (((unsigned)(2 * c)) ^ ((unsigned)((m & 7) << 4)));
                        *(unsigned long long*)(&Hl[p][off]) =
                            (unsigned long long)pk | ((unsigned long long)pk_hi << 32);
                    }
                }
            }

            // h[t] f32 store (+ hidden at last step); proj(t+1) prefetch
            if (t < T_STEPS - 1) {
                #pragma unroll
                for (int ct = 0; ct < 4; ++ct)
                    #pragma unroll
                    for (int q = 0; q < 4; ++q)
                        hbuf[((size_t)t * B_SZ + b0 + mrow + q) * NR + nb + ct * 16 + l15] = vv[ct][q];
                #pragma unroll
                for (int ct = 0; ct < 4; ++ct)
                    #pragma unroll
                    for (int q = 0; q < 4; ++q)
                        pj[ct][q] = hbuf[((size_t)(t + 1) * B_SZ + b0 + mrow + q) * NR + nb + ct * 16 + l15];
            } else {
                #pragma unroll
                for (int ct = 0; ct < 4; ++ct) {
                    #pragma unroll
                    for (int q = 0; q < 4; ++q) {
                        hbuf[((size_t)t * B_SZ + b0 + mrow + q) * NR + nb + ct * 16 + l15] = vv[ct][q];
                        hidout[(size_t)(b0 + mrow + q) * NR + nb + ct * 16 + l15] = vv[ct][q];
                    }
                }
            }
        }

        asm volatile("s_waitcnt lgkmcnt(0)" ::: "memory");
        __builtin_amdgcn_sched_barrier(0);
        __builtin_amdgcn_s_barrier();
        __builtin_amdgcn_sched_barrier(0);
    }
}

// ---------------------------------------------------------------------------
// Output head: softmax(hidden @ Wo^T + bo). 256 blocks (one batch row) x 256.
// ---------------------------------------------------------------------------
__global__ __launch_bounds__(256) void rnn_out(
    const float* __restrict__ Wo, const float* __restrict__ bo,
    float* __restrict__ dout)
{
    const float* hidden = dout + (size_t)NO * B_SZ + (size_t)T_STEPS * B_SZ * NR;
    const int b = blockIdx.x;
    const int tid = threadIdx.x, w = tid >> 6, l = tid & 63;

    __shared__ float hid[NR];
    __shared__ float lg[NO];

    if (tid < 128) {
        *(float4*)(&hid[tid * 4]) = *(const float4*)(hidden + (size_t)b * NR + tid * 4);
    }
    __syncthreads();

    #pragma unroll 1
    for (int jj = 0; jj < 16; ++jj) {
        const int j = w * 16 + jj;
        const float4* wr = (const float4*)(Wo + (size_t)j * NR + l * 8);
        const float4 a = wr[0], c = wr[1];
        const float4 h0 = *(const float4*)(&hid[l * 8]);
        const float4 h1 = *(const float4*)(&hid[l * 8 + 4]);
        float s = a.x * h0.x + a.y * h0.y + a.z * h0.z + a.w * h0.w
                + c.x * h1.x + c.y * h1.y + c.z * h1.z + c.w * h1.w;
        #pragma unroll
        for (int d = 32; d > 0; d >>= 1) s += __shfl_xor(s, d, 64);
        if (l == 0) lg[j] = s + bo[j];
    }
    __syncthreads();

    if (tid < 64) {
        const float x = lg[tid];
        float mx = x;
        #pragma unroll
        for (int d = 32; d > 0; d >>= 1) mx = fmaxf(mx, __shfl_xor(mx, d, 64));
        const float e = __expf(x - mx);
        float sum = e;
        #pragma unroll
        for (int d = 32; d > 0; d >>= 1) sum += __shfl_xor(sum, d, 64);
        dout[(size_t)b * NO + tid] = e / sum;
    }
}

extern "C" void kernel_launch(void* const* d_in, const int* in_sizes, int n_in,
                              void* d_out, int out_size, void* d_ws, size_t ws_size,
                              hipStream_t stream) {
    const float* inputs = (const float*)d_in[0];
    const float* noise  = (const float*)d_in[1];
    const float* Wi     = (const float*)d_in[2];
    const float* bi     = (const float*)d_in[3];
    const float* Wrec   = (const float*)d_in[4];
    const float* Wo     = (const float*)d_in[5];
    const float* bo     = (const float*)d_in[6];
    float* out = (float*)d_out;

    // exchange buffer: 16 grp x 2 parity x 2 dir x 2048 u64 = 1 MB
    unsigned long long* Xbuf = (unsigned long long*)d_ws;

    float* proj = out + (size_t)NO * B_SZ;   // proj lives in the h-output region

    // zero tags each launch (kills cross-run stale-tag matches)
    (void)hipMemsetAsync(d_ws, 0, (size_t)16 * 8192 * sizeof(unsigned long long), stream);
    proj_gemm<<<dim3(1024, 4), 256, 0, stream>>>(inputs, Wi, bi, noise, proj);
    rnn_scan<<<32, 512, 0, stream>>>(Wrec, out, Xbuf);
    rnn_out<<<256, 256, 0, stream>>>(Wo, bo, out);
}

// Round 12
// 653.786 us; speedup vs baseline: 1.8672x; 1.8672x over previous
//
#include <hip/hip_runtime.h>
#include <hip/hip_bf16.h>
#include <stdint.h>

#define T_STEPS 256
#define B_SZ    256
#define NI      128
#define NR      512
#define NO      64
#define BT      16    // batch rows per group
#define HALF_R  256   // output cols per WG (half of NR)
#define WBLK    224   // proj worker blocks
#define NTILE   2048  // proj tiles: 256 t x 2 row-halves x 4 col-blocks

typedef __attribute__((ext_vector_type(8))) short short8;
typedef __attribute__((ext_vector_type(4))) short short4v;
typedef __attribute__((ext_vector_type(4))) float f32x4;
typedef __attribute__((ext_vector_type(2))) unsigned long long u64x2;

__device__ __forceinline__ unsigned short f2bf(float f) {
    union { float f; unsigned u; } v; v.f = f;
    unsigned u = v.u;
    return (unsigned short)((u + 0x7FFFu + ((u >> 16) & 1u)) >> 16);
}

// 8 recurrent K-tiles with compile-time K-tile base (static Bh[] indices).
template<int KTB>
__device__ __forceinline__ void recur8(const unsigned char* Hbuf,
                                       const short8 (&Bh)[2][16],
                                       f32x4& acc0, f32x4& acc1,
                                       int l15, int l4, unsigned swzA) {
    #pragma unroll
    for (int kk = 0; kk < 8; ++kk) {
        const unsigned off = l15 * 1024 + (((unsigned)((KTB + kk) * 64 + l4 * 16)) ^ swzA);
        const short8 a = *(const short8*)(Hbuf + off);
        acc0 = __builtin_amdgcn_mfma_f32_16x16x32_bf16(a, Bh[0][KTB + kk], acc0, 0, 0, 0);
        acc1 = __builtin_amdgcn_mfma_f32_16x16x32_bf16(a, Bh[1][KTB + kk], acc1, 0, 0, 0);
    }
}

// ---------------------------------------------------------------------------
// Fused kernel: 256 blocks x 512 threads.
// Blocks 0..31  : persistent scan (R8 structure; grp = bid&15, half = bid>>4).
// Blocks 32..255: proj workers. proj[t,b,n] = bf16GEMM(inputs,Wi) + bi
//                 (+noise t<4), written t-ascending with agent-scope stores,
//                 ready-tag = f32 mantissa LSB = 1. Scan h-stores clear LSB,
//                 so graph replays can never see a stale tag. Workers never
//                 wait on the scan => no deadlock possible.
// ---------------------------------------------------------------------------
__global__ __launch_bounds__(512) void rnn_fused(
    const float* __restrict__ inputs, const float* __restrict__ Wi,
    const float* __restrict__ bi, const float* __restrict__ noise,
    const float* __restrict__ Wrec,
    float* __restrict__ dout, unsigned long long* __restrict__ Xbuf)
{
    __shared__ __align__(16) unsigned char smem[65536];
    const int bid = blockIdx.x;
    const int tid = threadIdx.x;
    const int w   = tid >> 6;
    const int l   = tid & 63;
    const int l15 = l & 15;
    const int l4  = l >> 4;

    float* hbuf = dout + (size_t)NO * B_SZ;          // proj in / h out
    unsigned* projU = (unsigned*)hbuf;

    if (bid >= 32) {
        // ------------------------- proj worker -------------------------
        unsigned char* Al = smem;            // 128 rows x 128 K bf16 (32 KB)
        unsigned char* Wl = smem + 32768;    // 128 n   x 128 K bf16 (32 KB)
        for (int tile = bid - 32; tile < NTILE; tile += WBLK) {
            const int t     = tile >> 3;
            const int sub   = tile & 7;
            const int brow0 = (sub >> 2) * 128;
            const int n0    = (sub & 3) * 128;
            const size_t gr0 = (size_t)t * B_SZ + brow0;

            __syncthreads();   // previous tile's LDS reads complete
            #pragma unroll
            for (int j = 0; j < 8; ++j) {
                const int f = j * 512 + tid, row = f >> 5, c4 = f & 31;
                const float4 v = *(const float4*)(inputs + (gr0 + row) * NI + c4 * 4);
                short4v pk;
                pk[0] = (short)f2bf(v.x); pk[1] = (short)f2bf(v.y);
                pk[2] = (short)f2bf(v.z); pk[3] = (short)f2bf(v.w);
                *(short4v*)(&Al[row * 256 + (((unsigned)(c4 * 8)) ^ ((row & 7) << 4))]) = pk;
            }
            #pragma unroll
            for (int j = 0; j < 8; ++j) {
                const int f = j * 512 + tid, r = f >> 5, c4 = f & 31;
                const float4 v = *(const float4*)(Wi + (size_t)(n0 + r) * NI + c4 * 4);
                short4v pk;
                pk[0] = (short)f2bf(v.x); pk[1] = (short)f2bf(v.y);
                pk[2] = (short)f2bf(v.z); pk[3] = (short)f2bf(v.w);
                *(short4v*)(&Wl[r * 256 + (((unsigned)(c4 * 8)) ^ ((r & 7) << 4))]) = pk;
            }
            __syncthreads();

            f32x4 acc[8];
            #pragma unroll
            for (int nt = 0; nt < 8; ++nt) acc[nt] = (f32x4){0.f, 0.f, 0.f, 0.f};
            #pragma unroll
            for (int kt = 0; kt < 4; ++kt) {
                const short8 a = *(const short8*)(
                    &Al[(w * 16 + l15) * 256 + (((unsigned)(kt * 64 + l4 * 16)) ^ ((l15 & 7) << 4))]);
                #pragma unroll
                for (int nt = 0; nt < 8; ++nt) {
                    const short8 b = *(const short8*)(
                        &Wl[(nt * 16 + l15) * 256 + (((unsigned)(kt * 64 + l4 * 16)) ^ ((l15 & 7) << 4))]);
                    acc[nt] = __builtin_amdgcn_mfma_f32_16x16x32_bf16(a, b, acc[nt], 0, 0, 0);
                }
            }
            #pragma unroll
            for (int nt = 0; nt < 8; ++nt) {
                const int n = n0 + nt * 16 + l15;
                const float bv = bi[n];
                #pragma unroll
                for (int q = 0; q < 4; ++q) {
                    const int b = brow0 + w * 16 + l4 * 4 + q;
                    float v = acc[nt][q] + bv;
                    if (t < 4) v += noise[((size_t)t * B_SZ + b) * NR + n];
                    __hip_atomic_store(projU + ((size_t)t * B_SZ + b) * NR + n,
                                       __float_as_uint(v) | 1u,
                                       __ATOMIC_RELAXED, __HIP_MEMORY_SCOPE_AGENT);
                }
            }
        }
        return;
    }

    // ----------------------------- scan (R8) -----------------------------
    const int grp  = bid & 15;
    const int half = bid >> 4;
    const int b0   = grp * BT;
    unsigned char (*Hl)[BT * 1024] = (unsigned char (*)[BT * 1024])smem; // 2x16KB

    // Wrec half -> register fragments
    short8 Bh[2][16];
    #pragma unroll
    for (int ct = 0; ct < 2; ++ct) {
        const int n = half * HALF_R + w * 32 + ct * 16 + l15;
        #pragma unroll
        for (int kt = 0; kt < 16; ++kt) {
            const float* src = Wrec + (size_t)n * NR + kt * 32 + l4 * 8;
            short8 f;
            #pragma unroll
            for (int j = 0; j < 8; ++j) f[j] = (short)f2bf(src[j]);
            Bh[ct][kt] = f;
        }
    }

    unsigned long long* Xg = Xbuf + (size_t)grp * 4096;
    float* hidout = hbuf + (size_t)T_STEPS * B_SZ * NR;

    const unsigned swzA = (unsigned)((l15 & 7) << 4);
    const int n0 = half * HALF_R + w * 32 + l15;   // ct=0 column
    const int n1 = n0 + 16;                        // ct=1 column
    const int mrow = l4 * 4;

    // prologue: acc = proj[0] (tagged spin until workers deliver t=0)
    f32x4 acc0, acc1;
    {
        unsigned u0[4], u1[4];
        for (;;) {
            unsigned m = 1u;
            #pragma unroll
            for (int q = 0; q < 4; ++q) {
                u0[q] = __hip_atomic_load(projU + (size_t)(b0 + mrow + q) * NR + n0,
                                          __ATOMIC_RELAXED, __HIP_MEMORY_SCOPE_AGENT);
                u1[q] = __hip_atomic_load(projU + (size_t)(b0 + mrow + q) * NR + n1,
                                          __ATOMIC_RELAXED, __HIP_MEMORY_SCOPE_AGENT);
                m &= u0[q] & u1[q];
            }
            if (m & 1u) break;
        }
        #pragma unroll
        for (int q = 0; q < 4; ++q) {
            acc0[q] = __uint_as_float(u0[q] & ~1u);
            acc1[q] = __uint_as_float(u1[q] & ~1u);
        }
    }

    unsigned upj0[4], upj1[4];

    for (int t = 0; t < T_STEPS; ++t) {
        const int pn = (t & 1) ^ 1;
        const int tag = ((t >> 1) & 1) ^ 1;   // exchange parity tag (1 first)

        // loop top: issue tagged proj[t+1] loads EARLY (~full step of cover).
        #pragma unroll
        for (int q = 0; q < 4; ++q) {
            upj0[q] = __hip_atomic_load(projU + ((size_t)(t + 1) * B_SZ + b0 + mrow + q) * NR + n0,
                                        __ATOMIC_RELAXED, __HIP_MEMORY_SCOPE_AGENT);
            upj1[q] = __hip_atomic_load(projU + ((size_t)(t + 1) * B_SZ + b0 + mrow + q) * NR + n1,
                                        __ATOMIC_RELAXED, __HIP_MEMORY_SCOPE_AGENT);
        }

        // phase A: partner-half recurrent contribution (exchanged h[t-1])
        if (t > 0) {
            if (half == 0) recur8<8>(&Hl[t & 1][0], Bh, acc0, acc1, l15, l4, swzA);
            else           recur8<0>(&Hl[t & 1][0], Bh, acc0, acc1, l15, l4, swzA);
        }

        float v0[4], v1[4];
        #pragma unroll
        for (int q = 0; q < 4; ++q) {
            v0[q] = fmaxf(acc0[q], 0.f);
            v1[q] = fmaxf(acc1[q], 0.f);
        }

        if (t == T_STEPS - 1) {
            #pragma unroll
            for (int q = 0; q < 4; ++q) {
                // clear mantissa LSB (proj ready-tag hygiene for graph replays)
                const float s0 = __uint_as_float(__float_as_uint(v0[q]) & ~1u);
                const float s1 = __uint_as_float(__float_as_uint(v1[q]) & ~1u);
                hbuf[((size_t)t * B_SZ + b0 + mrow + q) * NR + n0] = s0;
                hbuf[((size_t)t * B_SZ + b0 + mrow + q) * NR + n1] = s1;
                hidout[(size_t)(b0 + mrow + q) * NR + n0] = s0;
                hidout[(size_t)(b0 + mrow + q) * NR + n1] = s1;
            }
            break;
        }

        // phase B: pack 4 cols -> u64 on l%4==0 lanes; LDS own half (untagged)
        //          + tagged IF export (self-flagging; relu => sign bits free).
        {
            unsigned long long* Xh = Xg + (size_t)(pn * 2 + half) * 1024;
            const unsigned long long tagmask = tag ? 0x8000800080008000ULL : 0ULL;
            #pragma unroll
            for (int ct = 0; ct < 2; ++ct) {
                #pragma unroll
                for (int q = 0; q < 4; ++q) {
                    const float v = ct ? v1[q] : v0[q];
                    const float vo = __shfl_xor(v, 1, 64);
                    unsigned pk = (unsigned)f2bf(v) | ((unsigned)f2bf(vo) << 16);
                    const unsigned pk_hi = __shfl_xor(pk, 2, 64);
                    if ((l & 3) == 0) {
                        const int m = mrow + q;
                        const int c = w * 32 + ct * 16 + l15;     // own-half col, %4==0
                        const unsigned long long val =
                            (unsigned long long)pk | ((unsigned long long)pk_hi << 32);
                        const unsigned off = m * 1024 +
                            (((unsigned)(2 * (half * HALF_R + c))) ^ ((unsigned)((m & 7) << 4)));
                        *(unsigned long long*)(&Hl[pn][off]) = val;
                        __hip_atomic_store(Xh + m * 64 + (c >> 2), val | tagmask,
                                           __ATOMIC_RELAXED, __HIP_MEMORY_SCOPE_AGENT);
                    }
                }
            }
        }

        // barrier1: own-half LDS visible (lgkm only; vmem stays in flight)
        asm volatile("s_waitcnt lgkmcnt(0)" ::: "memory");
        __builtin_amdgcn_sched_barrier(0);
        __builtin_amdgcn_s_barrier();
        __builtin_amdgcn_sched_barrier(0);

        // phase E-prefetch: issue partner-line loads NOW; fly under phase D.
        const int prow = tid >> 5;
        const unsigned pkk = (unsigned)((2 * tid) & 63);          // even u64 index
        const unsigned long long* src =
            Xg + (size_t)(pn * 2 + (half ^ 1)) * 1024 + prow * 64 + pkk;
        unsigned long long pa = __hip_atomic_load(src,     __ATOMIC_RELAXED, __HIP_MEMORY_SCOPE_AGENT);
        unsigned long long pb = __hip_atomic_load(src + 1, __ATOMIC_RELAXED, __HIP_MEMORY_SCOPE_AGENT);
        __builtin_amdgcn_sched_barrier(0);   // pin load issue before phase D

        // phase D: h[t] store (LSB-cleared), own-half recurrent for t+1
        #pragma unroll
        for (int q = 0; q < 4; ++q) {
            hbuf[((size_t)t * B_SZ + b0 + mrow + q) * NR + n0] =
                __uint_as_float(__float_as_uint(v0[q]) & ~1u);
            hbuf[((size_t)t * B_SZ + b0 + mrow + q) * NR + n1] =
                __uint_as_float(__float_as_uint(v1[q]) & ~1u);
        }
        acc0 = (f32x4){0.f, 0.f, 0.f, 0.f};
        acc1 = (f32x4){0.f, 0.f, 0.f, 0.f};
        if (half == 0) recur8<0>(&Hl[pn][0], Bh, acc0, acc1, l15, l4, swzA);
        else           recur8<8>(&Hl[pn][0], Bh, acc0, acc1, l15, l4, swzA);

        // phase E: check prefetched tags; re-poll only if stale; place in LDS
        {
            const unsigned et = (unsigned)tag;
            for (;;) {
                if ((((unsigned)(pa >> 63)) == et) & (((unsigned)(pb >> 63)) == et)) break;
                pa = __hip_atomic_load(src,     __ATOMIC_RELAXED, __HIP_MEMORY_SCOPE_AGENT);
                pb = __hip_atomic_load(src + 1, __ATOMIC_RELAXED, __HIP_MEMORY_SCOPE_AGENT);
            }
            if (tag) { pa &= 0x7FFF7FFF7FFF7FFFULL; pb &= 0x7FFF7FFF7FFF7FFFULL; }
            u64x2 dd; dd[0] = pa; dd[1] = pb;
            const unsigned off = prow * 1024 +
                (((unsigned)((half ^ 1) * 512 + pkk * 8)) ^ ((unsigned)((prow & 7) << 4)));
            *(u64x2*)(&Hl[pn][off]) = dd;
        }

        // proj[t+1]: verify ready-tags on the prefetched values (spin if early)
        {
            unsigned m = 1u;
            #pragma unroll
            for (int q = 0; q < 4; ++q) m &= upj0[q] & upj1[q];
            while (!(m & 1u)) {
                m = 1u;
                #pragma unroll
                for (int q = 0; q < 4; ++q) {
                    upj0[q] = __hip_atomic_load(projU + ((size_t)(t + 1) * B_SZ + b0 + mrow + q) * NR + n0,
                                                __ATOMIC_RELAXED, __HIP_MEMORY_SCOPE_AGENT);
                    upj1[q] = __hip_atomic_load(projU + ((size_t)(t + 1) * B_SZ + b0 + mrow + q) * NR + n1,
                                                __ATOMIC_RELAXED, __HIP_MEMORY_SCOPE_AGENT);
                    m &= upj0[q] & upj1[q];
                }
            }
            #pragma unroll
            for (int q = 0; q < 4; ++q) {
                acc0[q] += __uint_as_float(upj0[q] & ~1u);
                acc1[q] += __uint_as_float(upj1[q] & ~1u);
            }
        }

        // barrier2: pulled partner half visible in LDS
        asm volatile("s_waitcnt lgkmcnt(0)" ::: "memory");
        __builtin_amdgcn_sched_barrier(0);
        __builtin_amdgcn_s_barrier();
        __builtin_amdgcn_sched_barrier(0);
    }
}

// ---------------------------------------------------------------------------
// Output head: softmax(hidden @ Wo^T + bo). 256 blocks (one batch row) x 256.
// ---------------------------------------------------------------------------
__global__ __launch_bounds__(256) void rnn_out(
    const float* __restrict__ Wo, const float* __restrict__ bo,
    float* __restrict__ dout)
{
    const float* hidden = dout + (size_t)NO * B_SZ + (size_t)T_STEPS * B_SZ * NR;
    const int b = blockIdx.x;
    const int tid = threadIdx.x, w = tid >> 6, l = tid & 63;

    __shared__ float hid[NR];
    __shared__ float lg[NO];

    if (tid < 128) {
        *(float4*)(&hid[tid * 4]) = *(const float4*)(hidden + (size_t)b * NR + tid * 4);
    }
    __syncthreads();

    #pragma unroll 1
    for (int jj = 0; jj < 16; ++jj) {
        const int j = w * 16 + jj;
        const float4* wr = (const float4*)(Wo + (size_t)j * NR + l * 8);
        const float4 a = wr[0], c = wr[1];
        const float4 h0 = *(const float4*)(&hid[l * 8]);
        const float4 h1 = *(const float4*)(&hid[l * 8 + 4]);
        float s = a.x * h0.x + a.y * h0.y + a.z * h0.z + a.w * h0.w
                + c.x * h1.x + c.y * h1.y + c.z * h1.z + c.w * h1.w;
        #pragma unroll
        for (int d = 32; d > 0; d >>= 1) s += __shfl_xor(s, d, 64);
        if (l == 0) lg[j] = s + bo[j];
    }
    __syncthreads();

    if (tid < 64) {
        const float x = lg[tid];
        float mx = x;
        #pragma unroll
        for (int d = 32; d > 0; d >>= 1) mx = fmaxf(mx, __shfl_xor(mx, d, 64));
        const float e = __expf(x - mx);
        float sum = e;
        #pragma unroll
        for (int d = 32; d > 0; d >>= 1) sum += __shfl_xor(sum, d, 64);
        dout[(size_t)b * NO + tid] = e / sum;
    }
}

extern "C" void kernel_launch(void* const* d_in, const int* in_sizes, int n_in,
                              void* d_out, int out_size, void* d_ws, size_t ws_size,
                              hipStream_t stream) {
    const float* inputs = (const float*)d_in[0];
    const float* noise  = (const float*)d_in[1];
    const float* Wi     = (const float*)d_in[2];
    const float* bi     = (const float*)d_in[3];
    const float* Wrec   = (const float*)d_in[4];
    const float* Wo     = (const float*)d_in[5];
    const float* bo     = (const float*)d_in[6];
    float* out = (float*)d_out;

    // exchange buffer: 16 grp x 2 parity x 2 half x 16 rows x 64 u64 = 512 KB
    unsigned long long* Xbuf = (unsigned long long*)d_ws;

    // zero exchange tags each launch (kills cross-run stale-tag matches)
    (void)hipMemsetAsync(d_ws, 0, 16 * 4096 * sizeof(unsigned long long), stream);
    rnn_fused<<<256, 512, 0, stream>>>(inputs, Wi, bi, noise, Wrec, out, Xbuf);
    rnn_out<<<256, 256, 0, stream>>>(Wo, bo, out);
}